// Round 1
// baseline (3643.201 us; speedup 1.0000x reference)
//
#include <hip/hip_runtime.h>
#include <hip/hip_bf16.h>
#include <math.h>

#define HIDDEN 4096
#define HALF   2048
#define NE     64
#define TOPK   8

// ---------- helpers for h storage precision (fp32 primary, bf16 fallback) ----
__device__ inline void hstore(float* p, float v) { *p = v; }
__device__ inline void hstore(__hip_bfloat16* p, float v) { *p = __float2bfloat16(v); }
__device__ inline float hload(const float* p) { return *p; }
__device__ inline float hload(const __hip_bfloat16* p) { return __bfloat162float(*p); }

// ---------------------------------------------------------------------------
// K1: h = gelu_exact(x @ W1 + b1)
// x[T,4096] row-major, W1[4096,2048] row-major, h[T,2048]
// 128x128 tile, BK=16, 256 threads, 8x8 micro-tile per thread, fp32 FMA.
// ---------------------------------------------------------------------------
template <typename HT>
__global__ __launch_bounds__(256) void gemm1_gelu(const float* __restrict__ x,
                                                  const float* __restrict__ W1,
                                                  const float* __restrict__ bias1,
                                                  HT* __restrict__ h) {
    __shared__ float As[16][132];   // A^T tile: As[k][m], +4 pad
    __shared__ float Bs[16][132];   // B tile:   Bs[k][n], +4 pad

    const int tid = threadIdx.x;
    const int m0  = blockIdx.x * 128;
    const int n0  = blockIdx.y * 128;
    const int tx  = tid & 15;       // 0..15 -> col groups
    const int ty  = tid >> 4;       // 0..15 -> row groups

    // global-load assignments
    const int ar = tid >> 2;              // 0..63  (row within tile, +64 for 2nd)
    const int ak = (tid & 3) << 2;        // k-offset {0,4,8,12}
    const int bk = tid >> 5;              // 0..7   (k row, +8 for 2nd)
    const int bn = (tid & 31) << 2;       // col offset {0..124}

    float acc[8][8];
#pragma unroll
    for (int i = 0; i < 8; ++i)
#pragma unroll
        for (int j = 0; j < 8; ++j) acc[i][j] = 0.f;

    const float* xA0 = x  + (size_t)(m0 + ar)      * HIDDEN + ak;
    const float* xA1 = x  + (size_t)(m0 + ar + 64) * HIDDEN + ak;
    const float* wB0 = W1 + (size_t)bk       * HALF + n0 + bn;
    const float* wB1 = W1 + (size_t)(bk + 8) * HALF + n0 + bn;

    for (int k0 = 0; k0 < HIDDEN; k0 += 16) {
        float4 a0  = *(const float4*)(xA0 + k0);
        float4 a1  = *(const float4*)(xA1 + k0);
        float4 b0  = *(const float4*)(wB0 + (size_t)k0 * HALF);
        float4 b1v = *(const float4*)(wB1 + (size_t)k0 * HALF);

        __syncthreads();   // previous iteration's LDS reads complete
        As[ak + 0][ar] = a0.x; As[ak + 1][ar] = a0.y;
        As[ak + 2][ar] = a0.z; As[ak + 3][ar] = a0.w;
        As[ak + 0][ar + 64] = a1.x; As[ak + 1][ar + 64] = a1.y;
        As[ak + 2][ar + 64] = a1.z; As[ak + 3][ar + 64] = a1.w;
        *(float4*)&Bs[bk][bn]     = b0;
        *(float4*)&Bs[bk + 8][bn] = b1v;
        __syncthreads();

#pragma unroll
        for (int kk = 0; kk < 16; ++kk) {
            float a[8], b[8];
            *(float4*)(a)     = *(const float4*)&As[kk][ty * 4];
            *(float4*)(a + 4) = *(const float4*)&As[kk][64 + ty * 4];
            *(float4*)(b)     = *(const float4*)&Bs[kk][tx * 4];
            *(float4*)(b + 4) = *(const float4*)&Bs[kk][64 + tx * 4];
#pragma unroll
            for (int i = 0; i < 8; ++i)
#pragma unroll
                for (int j = 0; j < 8; ++j)
                    acc[i][j] = fmaf(a[i], b[j], acc[i][j]);
        }
    }

    // epilogue: +bias, exact GELU, store h
    float bv[8];
    *(float4*)(bv)     = *(const float4*)(bias1 + n0 + tx * 4);
    *(float4*)(bv + 4) = *(const float4*)(bias1 + n0 + 64 + tx * 4);

#pragma unroll
    for (int ii = 0; ii < 2; ++ii) {
#pragma unroll
        for (int i = 0; i < 4; ++i) {
            const int row = m0 + ii * 64 + ty * 4 + i;
            HT* hp = h + (size_t)row * HALF + n0;
#pragma unroll
            for (int jj = 0; jj < 2; ++jj) {
#pragma unroll
                for (int j = 0; j < 4; ++j) {
                    float v = acc[ii * 4 + i][jj * 4 + j] + bv[jj * 4 + j];
                    float g = 0.5f * v * (1.0f + erff(v * 0.70710678118654752f));
                    hstore(hp + jj * 64 + tx * 4 + j, g);
                }
            }
        }
    }
}

// ---------------------------------------------------------------------------
// K2: logits[T,64] = h[T,2048] @ W2[2048,64] + b2. One block per token.
// 256 threads: lane e = tid&63, k-quarter q = tid>>6; reduce 4 partials in LDS.
// ---------------------------------------------------------------------------
template <typename HT>
__global__ __launch_bounds__(256) void gemm2(const HT* __restrict__ h,
                                             const float* __restrict__ W2,
                                             const float* __restrict__ bias2,
                                             float* __restrict__ logits) {
    __shared__ float hs[HALF];
    __shared__ float red[4][NE];
    const int tid = threadIdx.x;
    const size_t r = blockIdx.x;
    const HT* hr = h + r * HALF;
    for (int i = tid; i < HALF; i += 256) hs[i] = hload(hr + i);
    __syncthreads();
    const int e = tid & 63, q = tid >> 6;
    float s = 0.f;
    const float* w = W2 + e;
#pragma unroll 8
    for (int k = q * 512; k < q * 512 + 512; ++k)
        s = fmaf(hs[k], w[(size_t)k * NE], s);
    red[q][e] = s;
    __syncthreads();
    if (tid < 64)
        logits[r * NE + tid] = ((red[0][tid] + red[1][tid]) + (red[2][tid] + red[3][tid])) + bias2[tid];
}

// ---------------------------------------------------------------------------
// K3: per-token top-8 + softmax + scatter + mask. One wave (64 lanes) per token,
// lane == expert. Iterative max-with-index (lower index wins ties, matching
// jax.lax.top_k), softmax over the 8 winners (max = first winner).
// ---------------------------------------------------------------------------
__global__ __launch_bounds__(256) void topk_softmax(const float* __restrict__ logits,
                                                    const float* __restrict__ amask,
                                                    float* __restrict__ out, int T) {
    const int wave = threadIdx.x >> 6;
    const int lane = threadIdx.x & 63;
    const int r = blockIdx.x * 4 + wave;
    if (r >= T) return;

    const float v  = logits[(size_t)r * NE + lane];
    const float mk = amask[r];

    // router_logits (masked)
    out[(size_t)T * NE + (size_t)r * NE + lane] = v * mk;

    bool  sel = false;
    float m0 = 0.f, Z = 0.f;
#pragma unroll
    for (int it = 0; it < TOPK; ++it) {
        float cand = sel ? -INFINITY : v;
        int   idx  = lane;
#pragma unroll
        for (int off = 32; off; off >>= 1) {
            float ov = __shfl_xor(cand, off, 64);
            int   oi = __shfl_xor(idx,  off, 64);
            if (ov > cand || (ov == cand && oi < idx)) { cand = ov; idx = oi; }
        }
        if (it == 0) m0 = cand;          // max of selected set
        Z += expf(cand - m0);            // wave-uniform
        if (lane == idx) sel = true;
    }
    const float w = sel ? (expf(v - m0) / Z) : 0.f;
    out[(size_t)r * NE + lane] = w * mk;
}

// ---------------------------------------------------------------------------
extern "C" void kernel_launch(void* const* d_in, const int* in_sizes, int n_in,
                              void* d_out, int out_size, void* d_ws, size_t ws_size,
                              hipStream_t stream) {
    const float* x   = (const float*)d_in[0];
    const float* am  = (const float*)d_in[1];
    const float* W1  = (const float*)d_in[2];
    const float* b1  = (const float*)d_in[3];
    const float* W2  = (const float*)d_in[4];
    const float* b2  = (const float*)d_in[5];
    float* out = (float*)d_out;

    const int T = in_sizes[0] / HIDDEN;   // 16384

    float* logits = (float*)d_ws;
    const size_t logits_bytes = (size_t)T * NE * sizeof(float);
    const size_t h32_bytes    = (size_t)T * HALF * sizeof(float);
    const size_t h16_bytes    = (size_t)T * HALF * sizeof(__hip_bfloat16);

    dim3 g1(T / 128, HALF / 128);

    if (ws_size >= logits_bytes + h32_bytes) {
        float* h = (float*)((char*)d_ws + logits_bytes);
        hipLaunchKernelGGL((gemm1_gelu<float>), g1, dim3(256), 0, stream, x, W1, b1, h);
        hipLaunchKernelGGL((gemm2<float>), dim3(T), dim3(256), 0, stream, h, W2, b2, logits);
    } else {
        // fallback: bf16 h (half the scratch) — lower precision but functional
        __hip_bfloat16* h = (__hip_bfloat16*)((char*)d_ws + logits_bytes);
        hipLaunchKernelGGL((gemm1_gelu<__hip_bfloat16>), g1, dim3(256), 0, stream, x, W1, b1, h);
        hipLaunchKernelGGL((gemm2<__hip_bfloat16>), dim3(T), dim3(256), 0, stream, h, W2, b2, logits);
    }
    hipLaunchKernelGGL(topk_softmax, dim3(T / 4), dim3(256), 0, stream, logits, am, out, T);
}

// Round 2
// 1629.630 us; speedup vs baseline: 2.2356x; 2.2356x over previous
//
#include <hip/hip_runtime.h>
#include <hip/hip_bf16.h>
#include <math.h>

#define HIDDEN 4096
#define HALF   2048
#define NE     64
#define TOPK   8

typedef __attribute__((ext_vector_type(8))) short  short8;
typedef __attribute__((ext_vector_type(4))) float  floatx4;

// ---------- bf16 split helpers ------------------------------------------------
__device__ inline unsigned short bf16_rne(float v) {
    union { float f; unsigned u; } x; x.f = v;
    unsigned r = x.u + 0x7fffu + ((x.u >> 16) & 1u);
    return (unsigned short)(r >> 16);
}
__device__ inline float bf16_to_f(unsigned short b) {
    union { unsigned u; float f; } x; x.u = (unsigned)b << 16;
    return x.f;
}

// ---------- h storage precision helpers (fp32 primary, bf16 fallback) ---------
__device__ inline void hstore(float* p, float v) { *p = v; }
__device__ inline void hstore(__hip_bfloat16* p, float v) { *p = __float2bfloat16(v); }
__device__ inline float hload(const float* p) { return *p; }
__device__ inline float hload(const __hip_bfloat16* p) { return __bfloat162float(*p); }

// ---------------------------------------------------------------------------
// K1: h = gelu_exact(x @ W1 + b1) via split-bf16 3-pass MFMA.
// x[T,4096] row-major fp32, W1[4096,2048] row-major fp32, h[T,2048].
// Block: 256 thr (4 waves), tile 128x128, BK=32. Wave computes 64x64 as 4x4
// grid of 16x16x32 MFMA tiles. Conversion fp32 -> (hi,lo) bf16 fused into
// LDS staging. Error of dropped lo*lo term ~2^-16 rel -> fp32-level logits.
// LDS rows padded to 40 shorts: 80 B stride -> 20-bank step -> only 2-way
// conflicts (free per m136), keeps 16B alignment for ds_read_b128.
// ---------------------------------------------------------------------------
template <typename HT>
__global__ __launch_bounds__(256, 2) void gemm1_gelu_mfma(const float* __restrict__ x,
                                                          const float* __restrict__ W1,
                                                          const float* __restrict__ bias1,
                                                          HT* __restrict__ h) {
    __shared__ unsigned short Ah[128][40];
    __shared__ unsigned short Al[128][40];
    __shared__ unsigned short Bh[128][40];   // stored transposed: Bh[n][k]
    __shared__ unsigned short Bl[128][40];

    const int tid  = threadIdx.x;
    const int m0   = blockIdx.x * 128;
    const int n0   = blockIdx.y * 128;
    const int wave = tid >> 6, lane = tid & 63;
    const int wm   = (wave & 1) * 64;        // wave's m offset in tile
    const int wn   = (wave >> 1) * 64;       // wave's n offset in tile
    const int l15  = lane & 15;              // frag row/col
    const int q    = lane >> 4;              // k-quad

    // staging assignment: 128 rows x 2 k-halves (16 k each)
    const int sm = tid & 127;                // A row (m) / B col (n)
    const int kh = (tid >> 7) * 16;          // k-half offset {0,16}

    floatx4 acc[4][4];
#pragma unroll
    for (int i = 0; i < 4; ++i)
#pragma unroll
        for (int j = 0; j < 4; ++j) acc[i][j] = (floatx4)0.f;

    const float* xp = x  + (size_t)(m0 + sm) * HIDDEN + kh;
    const float* wp = W1 + (size_t)kh * HALF + n0 + sm;

    for (int k0 = 0; k0 < HIDDEN; k0 += 32) {
        // ---- global loads (issued before barrier: overlap other waves' MFMA)
        float4 av[4];
#pragma unroll
        for (int i = 0; i < 4; ++i) av[i] = *(const float4*)(xp + k0 + i * 4);
        float bv[16];
#pragma unroll
        for (int i = 0; i < 16; ++i) bv[i] = wp[(size_t)(k0 + i) * HALF];

        __syncthreads();   // previous iteration's frag reads complete

        // ---- convert A: 16 fp32 -> hi/lo bf16, 2x b128 writes each
        {
            unsigned short hi[16], lo[16];
#pragma unroll
            for (int i = 0; i < 4; ++i) {
                const float vs[4] = {av[i].x, av[i].y, av[i].z, av[i].w};
#pragma unroll
                for (int j = 0; j < 4; ++j) {
                    float v = vs[j];
                    unsigned short hb = bf16_rne(v);
                    hi[i * 4 + j] = hb;
                    lo[i * 4 + j] = bf16_rne(v - bf16_to_f(hb));
                }
            }
            *(short8*)&Ah[sm][kh]     = *(const short8*)&hi[0];
            *(short8*)&Ah[sm][kh + 8] = *(const short8*)&hi[8];
            *(short8*)&Al[sm][kh]     = *(const short8*)&lo[0];
            *(short8*)&Al[sm][kh + 8] = *(const short8*)&lo[8];
        }
        // ---- convert B (transposing [k][n] -> Bt[n][k])
        {
            unsigned short hi[16], lo[16];
#pragma unroll
            for (int i = 0; i < 16; ++i) {
                float v = bv[i];
                unsigned short hb = bf16_rne(v);
                hi[i] = hb;
                lo[i] = bf16_rne(v - bf16_to_f(hb));
            }
            *(short8*)&Bh[sm][kh]     = *(const short8*)&hi[0];
            *(short8*)&Bh[sm][kh + 8] = *(const short8*)&hi[8];
            *(short8*)&Bl[sm][kh]     = *(const short8*)&lo[0];
            *(short8*)&Bl[sm][kh + 8] = *(const short8*)&lo[8];
        }
        __syncthreads();

        // ---- fragment reads: A[m=l15][k=q*8+j], B[k=q*8+j][n=l15] (k-contig)
        short8 a_hi[4], a_lo[4], b_hi[4], b_lo[4];
#pragma unroll
        for (int t = 0; t < 4; ++t) {
            a_hi[t] = *(const short8*)&Ah[wm + t * 16 + l15][q * 8];
            a_lo[t] = *(const short8*)&Al[wm + t * 16 + l15][q * 8];
            b_hi[t] = *(const short8*)&Bh[wn + t * 16 + l15][q * 8];
            b_lo[t] = *(const short8*)&Bl[wn + t * 16 + l15][q * 8];
        }
        // ---- 3-pass split MFMA: hi*hi + lo*hi + hi*lo
#pragma unroll
        for (int i = 0; i < 4; ++i)
#pragma unroll
            for (int j = 0; j < 4; ++j) {
                acc[i][j] = __builtin_amdgcn_mfma_f32_16x16x32_bf16(a_hi[i], b_hi[j], acc[i][j], 0, 0, 0);
                acc[i][j] = __builtin_amdgcn_mfma_f32_16x16x32_bf16(a_lo[i], b_hi[j], acc[i][j], 0, 0, 0);
                acc[i][j] = __builtin_amdgcn_mfma_f32_16x16x32_bf16(a_hi[i], b_lo[j], acc[i][j], 0, 0, 0);
            }
    }

    // ---- epilogue: +bias, exact GELU, store h
    // C/D layout: col = lane&15, row = (lane>>4)*4 + reg  [m89/m91 verified]
#pragma unroll
    for (int j = 0; j < 4; ++j) {
        const int n = n0 + wn + j * 16 + l15;
        const float bb = bias1[n];
#pragma unroll
        for (int i = 0; i < 4; ++i) {
            const int mbase = m0 + wm + i * 16 + q * 4;
#pragma unroll
            for (int r = 0; r < 4; ++r) {
                float v = acc[i][j][r] + bb;
                float g = 0.5f * v * (1.0f + erff(v * 0.70710678118654752f));
                hstore(h + (size_t)(mbase + r) * HALF + n, g);
            }
        }
    }
}

// ---------------------------------------------------------------------------
// K2: logits[T,64] = h[T,2048] @ W2[2048,64] + b2. One block per token.
// ---------------------------------------------------------------------------
template <typename HT>
__global__ __launch_bounds__(256) void gemm2(const HT* __restrict__ h,
                                             const float* __restrict__ W2,
                                             const float* __restrict__ bias2,
                                             float* __restrict__ logits) {
    __shared__ float hs[HALF];
    __shared__ float red[4][NE];
    const int tid = threadIdx.x;
    const size_t r = blockIdx.x;
    const HT* hr = h + r * HALF;
    for (int i = tid; i < HALF; i += 256) hs[i] = hload(hr + i);
    __syncthreads();
    const int e = tid & 63, qq = tid >> 6;
    float s = 0.f;
    const float* w = W2 + e;
#pragma unroll 8
    for (int k = qq * 512; k < qq * 512 + 512; ++k)
        s = fmaf(hs[k], w[(size_t)k * NE], s);
    red[qq][e] = s;
    __syncthreads();
    if (tid < 64)
        logits[r * NE + tid] = ((red[0][tid] + red[1][tid]) + (red[2][tid] + red[3][tid])) + bias2[tid];
}

// ---------------------------------------------------------------------------
// K3: per-token top-8 + softmax + scatter + mask. One wave per token,
// lane == expert. Lower index wins ties (matches jax.lax.top_k).
// ---------------------------------------------------------------------------
__global__ __launch_bounds__(256) void topk_softmax(const float* __restrict__ logits,
                                                    const float* __restrict__ amask,
                                                    float* __restrict__ out, int T) {
    const int wave = threadIdx.x >> 6;
    const int lane = threadIdx.x & 63;
    const int r = blockIdx.x * 4 + wave;
    if (r >= T) return;

    const float v  = logits[(size_t)r * NE + lane];
    const float mk = amask[r];

    out[(size_t)T * NE + (size_t)r * NE + lane] = v * mk;   // router_logits

    bool  sel = false;
    float m0 = 0.f, Z = 0.f;
#pragma unroll
    for (int it = 0; it < TOPK; ++it) {
        float cand = sel ? -INFINITY : v;
        int   idx  = lane;
#pragma unroll
        for (int off = 32; off; off >>= 1) {
            float ov = __shfl_xor(cand, off, 64);
            int   oi = __shfl_xor(idx,  off, 64);
            if (ov > cand || (ov == cand && oi < idx)) { cand = ov; idx = oi; }
        }
        if (it == 0) m0 = cand;
        Z += expf(cand - m0);
        if (lane == idx) sel = true;
    }
    const float w = sel ? (expf(v - m0) / Z) : 0.f;
    out[(size_t)r * NE + lane] = w * mk;
}

// ---------------------------------------------------------------------------
extern "C" void kernel_launch(void* const* d_in, const int* in_sizes, int n_in,
                              void* d_out, int out_size, void* d_ws, size_t ws_size,
                              hipStream_t stream) {
    const float* x   = (const float*)d_in[0];
    const float* am  = (const float*)d_in[1];
    const float* W1  = (const float*)d_in[2];
    const float* b1  = (const float*)d_in[3];
    const float* W2  = (const float*)d_in[4];
    const float* b2  = (const float*)d_in[5];
    float* out = (float*)d_out;

    const int T = in_sizes[0] / HIDDEN;   // 16384

    float* logits = (float*)d_ws;
    const size_t logits_bytes = (size_t)T * NE * sizeof(float);
    const size_t h32_bytes    = (size_t)T * HALF * sizeof(float);

    dim3 g1(T / 128, HALF / 128);

    if (ws_size >= logits_bytes + h32_bytes) {
        float* h = (float*)((char*)d_ws + logits_bytes);
        hipLaunchKernelGGL((gemm1_gelu_mfma<float>), g1, dim3(256), 0, stream, x, W1, b1, h);
        hipLaunchKernelGGL((gemm2<float>), dim3(T), dim3(256), 0, stream, h, W2, b2, logits);
    } else {
        __hip_bfloat16* h = (__hip_bfloat16*)((char*)d_ws + logits_bytes);
        hipLaunchKernelGGL((gemm1_gelu_mfma<__hip_bfloat16>), g1, dim3(256), 0, stream, x, W1, b1, h);
        hipLaunchKernelGGL((gemm2<__hip_bfloat16>), dim3(T), dim3(256), 0, stream, h, W2, b2, logits);
    }
    hipLaunchKernelGGL(topk_softmax, dim3(T / 4), dim3(256), 0, stream, logits, am, out, T);
}